// Round 10
// baseline (1086.804 us; speedup 1.0000x reference)
//
#include <hip/hip_runtime.h>
#include <hip/hip_bf16.h>

#define NN 50000
#define NE 800000
#define NG 512
#define F0 92
#define FF 64
#define NB 41
#define HH 128
#define NBLK_SCAN 196          // ceil(NN/256)
#define NBATCH (NE / 64)
#define WBSZ (2 * 8 * 64 * 8)  // per-conv packed edge-weight elements (ushort)
#define PACK_EB 128

typedef __attribute__((ext_vector_type(4))) float f32x4;
typedef __attribute__((ext_vector_type(8))) short bf16x8;

__device__ __forceinline__ float softplusf(float x) {
    return fmaxf(x, 0.f) + __logf(1.f + __expf(-fabsf(x)));
}
__device__ __forceinline__ float sigmoidf(float x) {
    return __fdividef(1.f, 1.f + __expf(-x));
}
__device__ __forceinline__ ushort f2bf(float v) {
    __hip_bfloat16 b = __float2bfloat16(v);   // RTN
    return *reinterpret_cast<ushort*>(&b);
}

// ---------------- sort-by-src ----------------

__global__ __launch_bounds__(256) void hist_kernel(const int* __restrict__ ei,
                                                   int* __restrict__ cnt)
{
    for (int e = blockIdx.x * 256 + threadIdx.x; e < NE; e += gridDim.x * 256)
        atomicAdd(&cnt[ei[e]], 1);
}

__global__ __launch_bounds__(256) void scan1_kernel(const int* __restrict__ cnt,
                                                    int* __restrict__ bsum)
{
    __shared__ int sd[256];
    const int t = threadIdx.x;
    const int idx = blockIdx.x * 256 + t;
    sd[t] = (idx < NN) ? cnt[idx] : 0;
    __syncthreads();
    for (int s = 128; s > 0; s >>= 1) {
        if (t < s) sd[t] += sd[t + s];
        __syncthreads();
    }
    if (t == 0) bsum[blockIdx.x] = sd[0];
}

__global__ __launch_bounds__(256) void scan2_kernel(int* __restrict__ bsum)
{
    __shared__ int sd[256];
    const int t = threadIdx.x;
    const int v = (t < NBLK_SCAN) ? bsum[t] : 0;
    sd[t] = v;
    __syncthreads();
    for (int off = 1; off < 256; off <<= 1) {
        int a = (t >= off) ? sd[t - off] : 0;
        __syncthreads();
        sd[t] += a;
        __syncthreads();
    }
    if (t < NBLK_SCAN) bsum[t] = sd[t] - v;   // exclusive
}

__global__ __launch_bounds__(256) void scan3_kernel(const int* __restrict__ cnt,
                                                    const int* __restrict__ bsum,
                                                    int* __restrict__ cursor)
{
    __shared__ int sd[256];
    const int t = threadIdx.x;
    const int idx = blockIdx.x * 256 + t;
    const int v = (idx < NN) ? cnt[idx] : 0;
    sd[t] = v;
    __syncthreads();
    for (int off = 1; off < 256; off <<= 1) {
        int a = (t >= off) ? sd[t - off] : 0;
        __syncthreads();
        sd[t] += a;
        __syncthreads();
    }
    if (idx < NN) cursor[idx] = bsum[blockIdx.x] + sd[t] - v;
}

// one 16B record per edge at its sorted position
__global__ __launch_bounds__(256) void scatter_kernel(const int* __restrict__ ei,
                                                      int* __restrict__ cursor,
                                                      int4* __restrict__ esd)
{
    for (int e = blockIdx.x * 256 + threadIdx.x; e < NE; e += gridDim.x * 256) {
        const int s = ei[e];
        const int d = ei[NE + e];
        const int pos = atomicAdd(&cursor[s], 1);
        esd[pos] = make_int4(e, s, d, 0);
    }
}

// sorted-position bf16 A-fragment pack, cooperative gather (256 threads)
__global__ __launch_bounds__(256) void pack_kernel(const float* __restrict__ ea,
                                                   const int4* __restrict__ esd,
                                                   ushort* __restrict__ eaP)
{
    __shared__ float rowbuf[PACK_EB * NB];   // 21 KB
    __shared__ int eid[PACK_EB];
    const int t = threadIdx.x;
    const size_t base = (size_t)blockIdx.x * PACK_EB;
    if (t < PACK_EB) eid[t] = esd[base + t].x;
    __syncthreads();
    for (int i = t; i < PACK_EB * NB; i += 256) {
        const int e = i / NB, k = i - e * NB;
        rowbuf[i] = ea[(size_t)eid[e] * NB + k];
    }
    __syncthreads();
    uint* out = (uint*)eaP + base * 32;      // 32 uints per edge
    for (int i = t; i < PACK_EB * 32; i += 256) {
        const int gg = i >> 9;               // 512 uints per 16-edge group
        const int r = i & 511;
        const int t2 = r >> 8, lg = (r >> 6) & 3, rw = (r >> 2) & 15, ju = r & 3;
        const int e = gg * 16 + rw;
        const int k = t2 * 32 + lg * 8 + ju * 2;
        const float v0 = (k < NB) ? rowbuf[e * NB + k] : 0.f;
        const float v1 = (k + 1 < NB) ? rowbuf[e * NB + k + 1] : 0.f;
        out[i] = (uint)f2bf(v0) | ((uint)f2bf(v1) << 16);
    }
}

// packed B-fragments: wB[conv][kstep][ntile][lane][j] bf16
__global__ __launch_bounds__(256) void prep_kernel(
    const float* __restrict__ lnfW, const float* __restrict__ lnsW,
    ushort* __restrict__ wB)
{
    const int total = 3 * WBSZ;
    for (int idx = blockIdx.x * 256 + threadIdx.x; idx < total; idx += gridDim.x * 256) {
        const int j = idx & 7;
        const int lane = (idx >> 3) & 63;
        const int nt = (idx >> 9) & 7;
        const int t2 = (idx >> 12) & 1;
        const int i = idx >> 13;
        const int k = t2 * 32 + (lane >> 4) * 8 + j;
        const int col = (nt & 3) * 16 + (lane & 15);
        const float* W = (nt < 4 ? lnfW : lnsW) + (size_t)i * 169 * FF;
        wB[idx] = (k < NB) ? f2bf(W[(2 * FF + k) * FF + col]) : (ushort)0;
    }
}

// ---------------- network ----------------

// h = x @ embW + embb, fused column stats for bn1 of conv0
__global__ __launch_bounds__(256) void emb_kernel(
    const float* __restrict__ x, const float* __restrict__ W,
    const float* __restrict__ bias, float* __restrict__ h,
    float* __restrict__ stats0)
{
    __shared__ float sx[4][F0];
    __shared__ float sdr[2][4][FF];
    const int lane = threadIdx.x & 63;
    const int w = threadIdx.x >> 6;
    float wr[F0];
#pragma unroll
    for (int k = 0; k < F0; ++k) wr[k] = W[k * FF + lane];
    const float bv = bias[lane];
    float s = 0.f, s2 = 0.f;
    const int nit = NN / 4;
    for (int it = blockIdx.x; it < nit; it += gridDim.x) {
        const int n = it * 4 + w;
        if (lane < 46) {
            sx[w][lane * 2]     = x[n * F0 + lane * 2];
            sx[w][lane * 2 + 1] = x[n * F0 + lane * 2 + 1];
        }
        __syncthreads();
        float acc = bv;
#pragma unroll
        for (int k4 = 0; k4 < F0 / 4; ++k4) {
            float4 q = *(const float4*)&sx[w][k4 * 4];
            acc = fmaf(q.x, wr[k4 * 4 + 0], acc);
            acc = fmaf(q.y, wr[k4 * 4 + 1], acc);
            acc = fmaf(q.z, wr[k4 * 4 + 2], acc);
            acc = fmaf(q.w, wr[k4 * 4 + 3], acc);
        }
        h[n * FF + lane] = acc;
        s += acc;
        s2 = fmaf(acc, acc, s2);
        __syncthreads();
    }
    sdr[0][w][lane] = s;
    sdr[1][w][lane] = s2;
    __syncthreads();
    if (threadIdx.x < FF) {
        const int f = threadIdx.x;
        atomicAdd(&stats0[f],      sdr[0][0][f] + sdr[0][1][f] + sdr[0][2][f] + sdr[0][3][f]);
        atomicAdd(&stats0[FF + f], sdr[1][0][f] + sdr[1][1][f] + sdr[1][2][f] + sdr[1][3][f]);
    }
}

// column sums / sumsq (for agg / bn2)
__global__ __launch_bounds__(256) void stats_kernel(
    const float* __restrict__ src, float* __restrict__ stats)
{
    __shared__ float sd[2][4][FF];
    const int f = threadIdx.x & 63;
    const int r = threadIdx.x >> 6;
    float s = 0.f, s2 = 0.f;
    for (int n = blockIdx.x * 4 + r; n < NN; n += gridDim.x * 4) {
        float v = src[n * FF + f];
        s += v;
        s2 = fmaf(v, v, s2);
    }
    sd[0][r][f] = s;
    sd[1][r][f] = s2;
    __syncthreads();
    if (threadIdx.x < FF) {
        atomicAdd(&stats[f],      sd[0][0][f] + sd[0][1][f] + sd[0][2][f] + sd[0][3][f]);
        atomicAdd(&stats[FF + f], sd[1][0][f] + sd[1][1][f] + sd[1][2][f] + sd[1][3][f]);
    }
}

// xn = bn1(h); pS[n*128+2f+{0,1}] = xn@{Wf,Ws}_src + {bf,bs}; pD likewise (dst rows)
// Barrier-free: each wave recomputes xv for its node and stages in its OWN LDS
// row (same-wave DS ordering, no __syncthreads).
__global__ __launch_bounds__(256) void node_kernel(
    const float* __restrict__ h, const float* __restrict__ stats,
    const float* __restrict__ gbn, const float* __restrict__ bbn,
    const float* __restrict__ Wf, const float* __restrict__ Ws,
    const float* __restrict__ bf, const float* __restrict__ bs,
    float* __restrict__ xn, float* __restrict__ pS, float* __restrict__ pD)
{
    __shared__ float sx[4][FF];
    const int lane = threadIdx.x & 63;
    const int w = threadIdx.x >> 6;
    const float* W = (w < 2) ? Wf : Ws;
    const int rowbase = (w & 1) * FF;
    float wr[FF];
#pragma unroll
    for (int k = 0; k < FF; ++k) wr[k] = W[(rowbase + k) * FF + lane];
    const float inv = 1.f / (float)NN;
    const float mean = stats[lane] * inv;
    const float var = stats[FF + lane] * inv - mean * mean;
    const float A = rsqrtf(var + 1e-5f) * gbn[lane];
    const float B = fmaf(-mean, A, bbn[lane]);
    float bias = 0.f;
    if (w == 0) bias = bf[lane];
    if (w == 2) bias = bs[lane];
    float* outp = ((w & 1) ? pD : pS) + ((w >> 1) & 1);
    for (int n = blockIdx.x; n < NN; n += gridDim.x) {
        const float xv = fmaf(h[n * FF + lane], A, B);
        if (w == 0) xn[n * FF + lane] = xv;
        sx[w][lane] = xv;                     // own row; wave-order DS, no barrier
        float acc = bias;
#pragma unroll
        for (int k4 = 0; k4 < FF / 4; ++k4) {
            float4 q = *(const float4*)&sx[w][k4 * 4];
            acc = fmaf(q.x, wr[k4 * 4 + 0], acc);
            acc = fmaf(q.y, wr[k4 * 4 + 1], acc);
            acc = fmaf(q.z, wr[k4 * 4 + 2], acc);
            acc = fmaf(q.w, wr[k4 * 4 + 3], acc);
        }
        outp[(size_t)n * 128 + 2 * lane] = acc;
    }
}

// MFMA edge kernel: sorted eaP (coalesced), in-register sorted-run seg-sum
// epilogue, fully unrolled body (compiler software-pipelines loads).
__global__ __launch_bounds__(256)
void edge_kernel(const ushort* __restrict__ eaP, const int4* __restrict__ esd,
                 const ushort* __restrict__ wB,
                 const float* __restrict__ pS, const float* __restrict__ pD,
                 float* __restrict__ agg)
{
    __shared__ ushort wlds[WBSZ];           // 16 KB packed B-fragments
    const int t = threadIdx.x, lane = t & 63;
    for (int i = t; i < WBSZ / 8; i += 256)
        ((int4*)wlds)[i] = ((const int4*)wB)[i];
    __syncthreads();
    const int le = lane >> 4, lf = lane & 15;
    const int nw = (gridDim.x * 256) >> 6;
    const int gw = (blockIdx.x * 256 + t) >> 6;

    for (int b = gw; b < NBATCH; b += nw) {
        const int4 rec = esd[b * 64 + lane];
#pragma unroll
        for (int g = 0; g < 4; ++g) {
            const bf16x8 af0 = *(const bf16x8*)&eaP[(((size_t)(b * 4 + g) * 2 + 0) * 64 + lane) * 8];
            const bf16x8 af1 = *(const bf16x8*)&eaP[(((size_t)(b * 4 + g) * 2 + 1) * 64 + lane) * 8];
            const int sv0 = __shfl(rec.y, g * 16 + le * 4 + 0, 64);
            const int sv1 = __shfl(rec.y, g * 16 + le * 4 + 1, 64);
            const int sv2 = __shfl(rec.y, g * 16 + le * 4 + 2, 64);
            const int sv3 = __shfl(rec.y, g * 16 + le * 4 + 3, 64);
            const int dv0 = __shfl(rec.z, g * 16 + le * 4 + 0, 64);
            const int dv1 = __shfl(rec.z, g * 16 + le * 4 + 1, 64);
            const int dv2 = __shfl(rec.z, g * 16 + le * 4 + 2, 64);
            const int dv3 = __shfl(rec.z, g * 16 + le * 4 + 3, 64);
#pragma unroll
            for (int p = 0; p < 4; ++p) {
                const bf16x8 bG0 = *(const bf16x8*)&wlds[((0 * 8 + p) * 64 + lane) * 8];
                const bf16x8 bG1 = *(const bf16x8*)&wlds[((1 * 8 + p) * 64 + lane) * 8];
                const bf16x8 bC0 = *(const bf16x8*)&wlds[((0 * 8 + p + 4) * 64 + lane) * 8];
                const bf16x8 bC1 = *(const bf16x8*)&wlds[((1 * 8 + p + 4) * 64 + lane) * 8];
                f32x4 aG = {0.f, 0.f, 0.f, 0.f}, aC = {0.f, 0.f, 0.f, 0.f};
                aG = __builtin_amdgcn_mfma_f32_16x16x32_bf16(af0, bG0, aG, 0, 0, 0);
                aG = __builtin_amdgcn_mfma_f32_16x16x32_bf16(af1, bG1, aG, 0, 0, 0);
                aC = __builtin_amdgcn_mfma_f32_16x16x32_bf16(af0, bC0, aC, 0, 0, 0);
                aC = __builtin_amdgcn_mfma_f32_16x16x32_bf16(af1, bC1, aC, 0, 0, 0);
                const int fo = 2 * (p * 16 + lf);
                const float2 s20 = *(const float2*)(pS + (size_t)sv0 * 128 + fo);
                const float2 d20 = *(const float2*)(pD + (size_t)dv0 * 128 + fo);
                const float2 s21 = *(const float2*)(pS + (size_t)sv1 * 128 + fo);
                const float2 d21 = *(const float2*)(pD + (size_t)dv1 * 128 + fo);
                const float2 s22 = *(const float2*)(pS + (size_t)sv2 * 128 + fo);
                const float2 d22 = *(const float2*)(pD + (size_t)dv2 * 128 + fo);
                const float2 s23 = *(const float2*)(pS + (size_t)sv3 * 128 + fo);
                const float2 d23 = *(const float2*)(pD + (size_t)dv3 * 128 + fo);
                const float m0 = sigmoidf(aG[0] + s20.x + d20.x) * softplusf(aC[0] + s20.y + d20.y);
                const float m1 = sigmoidf(aG[1] + s21.x + d21.x) * softplusf(aC[1] + s21.y + d21.y);
                const float m2 = sigmoidf(aG[2] + s22.x + d22.x) * softplusf(aC[2] + s22.y + d22.y);
                const float m3 = sigmoidf(aG[3] + s23.x + d23.x) * softplusf(aC[3] + s23.y + d23.y);
                const int fcol = p * 16 + lf;
                float run = m0;
                if (sv1 == sv0) run += m1;
                else { unsafeAtomicAdd(&agg[(size_t)sv0 * FF + fcol], run); run = m1; }
                if (sv2 == sv1) run += m2;
                else { unsafeAtomicAdd(&agg[(size_t)sv1 * FF + fcol], run); run = m2; }
                if (sv3 == sv2) run += m3;
                else { unsafeAtomicAdd(&agg[(size_t)sv2 * FF + fcol], run); run = m3; }
                unsafeAtomicAdd(&agg[(size_t)sv3 * FF + fcol], run);
            }
        }
    }
}

// h = softplus(bn2(agg) + xn); BN affine from raw sums; fused stats for next
// conv's bn1; last conv pools
__global__ __launch_bounds__(256) void update_kernel(
    const float* __restrict__ agg, const float* __restrict__ xn,
    const float* __restrict__ stats,
    const float* __restrict__ gbn, const float* __restrict__ bbn,
    float* __restrict__ h, const int* __restrict__ batch,
    float* __restrict__ pool, float* __restrict__ pcnt,
    float* __restrict__ statsNext, const int do_pool)
{
    __shared__ float sdr[2][4][FF];
    const int myf = threadIdx.x & 63;
    const float inv = 1.f / (float)NN;
    const float mean = stats[myf] * inv;
    const float var = stats[FF + myf] * inv - mean * mean;
    const float A = rsqrtf(var + 1e-5f) * gbn[myf];
    const float B = fmaf(-mean, A, bbn[myf]);
    float s = 0.f, s2 = 0.f;
    const int total = NN * FF;
    for (int idx = blockIdx.x * blockDim.x + threadIdx.x; idx < total;
         idx += gridDim.x * blockDim.x) {
        const int n = idx >> 6;
        const float v = softplusf(fmaf(agg[idx], A, B) + xn[idx]);
        if (do_pool) {
            const int g = batch[n];
            unsafeAtomicAdd(&pool[g * FF + myf], v);
            if (myf == 0) unsafeAtomicAdd(&pcnt[g], 1.f);
        } else {
            h[idx] = v;
            s += v;
            s2 = fmaf(v, v, s2);
        }
    }
    if (!do_pool) {
        const int r = threadIdx.x >> 6;
        sdr[0][r][myf] = s;
        sdr[1][r][myf] = s2;
        __syncthreads();
        if (threadIdx.x < FF) {
            atomicAdd(&statsNext[myf],      sdr[0][0][myf] + sdr[0][1][myf] + sdr[0][2][myf] + sdr[0][3][myf]);
            atomicAdd(&statsNext[FF + myf], sdr[1][0][myf] + sdr[1][1][myf] + sdr[1][2][myf] + sdr[1][3][myf]);
        }
    }
}

__global__ __launch_bounds__(128) void readout_kernel(
    const float* __restrict__ pool, const float* __restrict__ pcnt,
    const float* __restrict__ fc1W, const float* __restrict__ fc1b,
    const float* __restrict__ outW, const float* __restrict__ outb,
    float* __restrict__ out)
{
    __shared__ float sp[FF];
    __shared__ float red[2];
    const int g = blockIdx.x;
    const int t = threadIdx.x;
    if (t < FF) {
        const float c = fmaxf(pcnt[g], 1.f);
        sp[t] = softplusf(pool[g * FF + t] / c);
    }
    __syncthreads();
    float a = fc1b[t];
#pragma unroll
    for (int k = 0; k < FF; ++k) a = fmaf(sp[k], fc1W[k * HH + t], a);
    float o = softplusf(a) * outW[t];
#pragma unroll
    for (int off = 32; off > 0; off >>= 1) o += __shfl_down(o, off, 64);
    if ((t & 63) == 0) red[t >> 6] = o;
    __syncthreads();
    if (t == 0) out[g] = red[0] + red[1] + outb[0];
}

extern "C" void kernel_launch(void* const* d_in, const int* in_sizes, int n_in,
                              void* d_out, int out_size, void* d_ws, size_t ws_size,
                              hipStream_t stream)
{
    const float* x     = (const float*)d_in[0];
    const int*   ei    = (const int*)  d_in[1];
    const float* ea    = (const float*)d_in[2];
    const int*   batch = (const int*)  d_in[3];
    const float* embW  = (const float*)d_in[4];
    const float* embb  = (const float*)d_in[5];
    const float* bn1g  = (const float*)d_in[6];
    const float* bn1b  = (const float*)d_in[7];
    const float* bn2g  = (const float*)d_in[8];
    const float* bn2b  = (const float*)d_in[9];
    const float* lnfW  = (const float*)d_in[10];
    const float* lnfb  = (const float*)d_in[11];
    const float* lnsW  = (const float*)d_in[12];
    const float* lnsb  = (const float*)d_in[13];
    const float* fc1W  = (const float*)d_in[14];
    const float* fc1b  = (const float*)d_in[15];
    const float* outW  = (const float*)d_in[16];
    const float* outb  = (const float*)d_in[17];

    float* ws      = (float*)d_ws;
    float* h       = ws;
    float* xn      = h   + (size_t)NN * FF;
    float* pS      = xn  + (size_t)NN * FF;      // [NN][128] interleaved gate/core
    float* pD      = pS  + (size_t)NN * 128;
    float* agg     = pD  + (size_t)NN * 128;
    float* pool    = agg + (size_t)NN * FF;
    float* pcnt    = pool + (size_t)NG * FF;
    float* statsB1 = pcnt + NG;                  // 3 x 256 (raw sums)
    float* statsB2 = statsB1 + 3 * 256;          // 3 x 256 (raw sums)
    int*   cnt     = (int*)(statsB2 + 3 * 256);  // NN
    int*   cursor  = cnt + NN;                   // NN
    int*   bsum    = cursor + NN;                // 256
    int4*  esd     = (int4*)(bsum + 256);        // NE x 16B
    ushort* wB     = (ushort*)(esd + NE);        // 3 * WBSZ
    ushort* eaP    = wB + 3 * WBSZ;              // NE * 64 bf16 (sorted order)

    hipMemsetAsync(cnt, 0, NN * sizeof(int), stream);
    hipMemsetAsync(pool, 0, (NG * FF + NG + 6 * 256) * sizeof(float), stream);

    hist_kernel<<<2048, 256, 0, stream>>>(ei, cnt);
    scan1_kernel<<<NBLK_SCAN, 256, 0, stream>>>(cnt, bsum);
    scan2_kernel<<<1, 256, 0, stream>>>(bsum);
    scan3_kernel<<<NBLK_SCAN, 256, 0, stream>>>(cnt, bsum, cursor);
    scatter_kernel<<<2048, 256, 0, stream>>>(ei, cursor, esd);
    pack_kernel<<<NE / PACK_EB, 256, 0, stream>>>(ea, esd, eaP);
    prep_kernel<<<96, 256, 0, stream>>>(lnfW, lnsW, wB);
    emb_kernel<<<1024, 256, 0, stream>>>(x, embW, embb, h, statsB1);

    for (int i = 0; i < 3; ++i) {
        const float* Wf  = lnfW + (size_t)i * 169 * FF;
        const float* Wsp = lnsW + (size_t)i * 169 * FF;
        float* s1 = statsB1 + (size_t)i * 256;
        float* s2 = statsB2 + (size_t)i * 256;
        node_kernel<<<2048, 256, 0, stream>>>(h, s1, bn1g + i * FF, bn1b + i * FF,
                                              Wf, Wsp, lnfb + i * FF, lnsb + i * FF,
                                              xn, pS, pD);
        hipMemsetAsync(agg, 0, (size_t)NN * FF * sizeof(float), stream);
        edge_kernel<<<2048, 256, 0, stream>>>(eaP, esd, wB + (size_t)i * WBSZ,
                                              pS, pD, agg);
        stats_kernel<<<256, 256, 0, stream>>>(agg, s2);
        update_kernel<<<2048, 256, 0, stream>>>(agg, xn, s2, bn2g + i * FF, bn2b + i * FF,
                                                h, batch, pool, pcnt,
                                                statsB1 + (size_t)(i + 1 < 3 ? i + 1 : 0) * 256,
                                                (i == 2) ? 1 : 0);
    }
    readout_kernel<<<NG, HH, 0, stream>>>(pool, pcnt, fc1W, fc1b, outW, outb, (float*)d_out);
}

// Round 11
// 971.381 us; speedup vs baseline: 1.1188x; 1.1188x over previous
//
#include <hip/hip_runtime.h>
#include <hip/hip_bf16.h>

#define NN 50000
#define NE 800000
#define NG 512
#define F0 92
#define FF 64
#define NB 41
#define HH 128
#define NBLK_SCAN 196          // ceil(NN/256)
#define NBATCH (NE / 64)
#define WBSZ (2 * 8 * 64 * 8)  // per-conv packed edge-weight elements (ushort)

typedef __attribute__((ext_vector_type(4))) float f32x4;
typedef __attribute__((ext_vector_type(8))) short bf16x8;

__device__ __forceinline__ float softplusf(float x) {
    return fmaxf(x, 0.f) + __logf(1.f + __expf(-fabsf(x)));
}
__device__ __forceinline__ float sigmoidf(float x) {
    return __fdividef(1.f, 1.f + __expf(-x));
}
__device__ __forceinline__ ushort f2bf(float v) {
    __hip_bfloat16 b = __float2bfloat16(v);   // RTN
    return *reinterpret_cast<ushort*>(&b);
}

// ---------------- sort-by-src ----------------

__global__ __launch_bounds__(256) void hist_kernel(const int* __restrict__ ei,
                                                   int* __restrict__ cnt)
{
    for (int e = blockIdx.x * 256 + threadIdx.x; e < NE; e += gridDim.x * 256)
        atomicAdd(&cnt[ei[e]], 1);
}

__global__ __launch_bounds__(256) void scan1_kernel(const int* __restrict__ cnt,
                                                    int* __restrict__ bsum)
{
    __shared__ int sd[256];
    const int t = threadIdx.x;
    const int idx = blockIdx.x * 256 + t;
    sd[t] = (idx < NN) ? cnt[idx] : 0;
    __syncthreads();
    for (int s = 128; s > 0; s >>= 1) {
        if (t < s) sd[t] += sd[t + s];
        __syncthreads();
    }
    if (t == 0) bsum[blockIdx.x] = sd[0];
}

__global__ __launch_bounds__(256) void scan2_kernel(int* __restrict__ bsum)
{
    __shared__ int sd[256];
    const int t = threadIdx.x;
    const int v = (t < NBLK_SCAN) ? bsum[t] : 0;
    sd[t] = v;
    __syncthreads();
    for (int off = 1; off < 256; off <<= 1) {
        int a = (t >= off) ? sd[t - off] : 0;
        __syncthreads();
        sd[t] += a;
        __syncthreads();
    }
    if (t < NBLK_SCAN) bsum[t] = sd[t] - v;   // exclusive
}

__global__ __launch_bounds__(256) void scan3_kernel(const int* __restrict__ cnt,
                                                    const int* __restrict__ bsum,
                                                    int* __restrict__ cursor)
{
    __shared__ int sd[256];
    const int t = threadIdx.x;
    const int idx = blockIdx.x * 256 + t;
    const int v = (idx < NN) ? cnt[idx] : 0;
    sd[t] = v;
    __syncthreads();
    for (int off = 1; off < 256; off <<= 1) {
        int a = (t >= off) ? sd[t - off] : 0;
        __syncthreads();
        sd[t] += a;
        __syncthreads();
    }
    if (idx < NN) cursor[idx] = bsum[blockIdx.x] + sd[t] - v;
}

// one 16B record per edge at its sorted position
__global__ __launch_bounds__(256) void scatter_kernel(const int* __restrict__ ei,
                                                      int* __restrict__ cursor,
                                                      int4* __restrict__ esd)
{
    for (int e = blockIdx.x * 256 + threadIdx.x; e < NE; e += gridDim.x * 256) {
        const int s = ei[e];
        const int d = ei[NE + e];
        const int pos = atomicAdd(&cursor[s], 1);
        esd[pos] = make_int4(e, s, d, 0);
    }
}

// gather-side bf16 A-fragment packing into SORTED position (R6-proven config)
// eaP layout: [group][kstep][lane][j] bf16 where edge = group*16 + (pos&15),
// k = kstep*32 + lg*8 + j  (zero-padded k>=41)
__global__ __launch_bounds__(256) void pack_kernel(const float* __restrict__ ea,
                                                   const int4* __restrict__ esd,
                                                   ushort* __restrict__ eaP)
{
    const int pos = blockIdx.x * 256 + threadIdx.x;
    if (pos >= NE) return;
    const int e = esd[pos].x;
    const float* row = ea + (size_t)e * NB;
    const int gg = pos >> 4, rw = pos & 15;
#pragma unroll
    for (int t2 = 0; t2 < 2; ++t2)
#pragma unroll
        for (int lg = 0; lg < 4; ++lg) {
            ushort buf[8] __attribute__((aligned(16)));
#pragma unroll
            for (int j = 0; j < 8; ++j) {
                const int k = t2 * 32 + lg * 8 + j;
                buf[j] = (k < NB) ? f2bf(row[k]) : (ushort)0;
            }
            *(int4*)&eaP[(((size_t)gg * 2 + t2) * 64 + lg * 16 + rw) * 8] =
                *(const int4*)buf;
        }
}

// packed B-fragments: wB[conv][kstep][ntile][lane][j] bf16
__global__ __launch_bounds__(256) void prep_kernel(
    const float* __restrict__ lnfW, const float* __restrict__ lnsW,
    ushort* __restrict__ wB)
{
    const int total = 3 * WBSZ;
    for (int idx = blockIdx.x * 256 + threadIdx.x; idx < total; idx += gridDim.x * 256) {
        const int j = idx & 7;
        const int lane = (idx >> 3) & 63;
        const int nt = (idx >> 9) & 7;
        const int t2 = (idx >> 12) & 1;
        const int i = idx >> 13;
        const int k = t2 * 32 + (lane >> 4) * 8 + j;
        const int col = (nt & 3) * 16 + (lane & 15);
        const float* W = (nt < 4 ? lnfW : lnsW) + (size_t)i * 169 * FF;
        wB[idx] = (k < NB) ? f2bf(W[(2 * FF + k) * FF + col]) : (ushort)0;
    }
}

// ---------------- network ----------------

// h = x @ embW + embb, fused column stats; barrier-free wave-local staging
__global__ __launch_bounds__(256) void emb_kernel(
    const float* __restrict__ x, const float* __restrict__ W,
    const float* __restrict__ bias, float* __restrict__ h,
    float* __restrict__ stats0)
{
    __shared__ float sx[4][F0];
    __shared__ float sdr[2][4][FF];
    const int lane = threadIdx.x & 63;
    const int w = threadIdx.x >> 6;
    float wr[F0];
#pragma unroll
    for (int k = 0; k < F0; ++k) wr[k] = W[k * FF + lane];
    const float bv = bias[lane];
    float s = 0.f, s2 = 0.f;
    const int nit = NN / 4;
    for (int it = blockIdx.x; it < nit; it += gridDim.x) {
        const int n = it * 4 + w;
        if (lane < 46) {
            sx[w][lane * 2]     = x[n * F0 + lane * 2];
            sx[w][lane * 2 + 1] = x[n * F0 + lane * 2 + 1];
        }
        // own wave's row: DS ordering within wave, no barrier
        float acc = bv;
#pragma unroll
        for (int k4 = 0; k4 < F0 / 4; ++k4) {
            float4 q = *(const float4*)&sx[w][k4 * 4];
            acc = fmaf(q.x, wr[k4 * 4 + 0], acc);
            acc = fmaf(q.y, wr[k4 * 4 + 1], acc);
            acc = fmaf(q.z, wr[k4 * 4 + 2], acc);
            acc = fmaf(q.w, wr[k4 * 4 + 3], acc);
        }
        h[n * FF + lane] = acc;
        s += acc;
        s2 = fmaf(acc, acc, s2);
    }
    sdr[0][w][lane] = s;
    sdr[1][w][lane] = s2;
    __syncthreads();
    if (threadIdx.x < FF) {
        const int f = threadIdx.x;
        atomicAdd(&stats0[f],      sdr[0][0][f] + sdr[0][1][f] + sdr[0][2][f] + sdr[0][3][f]);
        atomicAdd(&stats0[FF + f], sdr[1][0][f] + sdr[1][1][f] + sdr[1][2][f] + sdr[1][3][f]);
    }
}

// column sums / sumsq (for agg / bn2)
__global__ __launch_bounds__(256) void stats_kernel(
    const float* __restrict__ src, float* __restrict__ stats)
{
    __shared__ float sd[2][4][FF];
    const int f = threadIdx.x & 63;
    const int r = threadIdx.x >> 6;
    float s = 0.f, s2 = 0.f;
    for (int n = blockIdx.x * 4 + r; n < NN; n += gridDim.x * 4) {
        float v = src[n * FF + f];
        s += v;
        s2 = fmaf(v, v, s2);
    }
    sd[0][r][f] = s;
    sd[1][r][f] = s2;
    __syncthreads();
    if (threadIdx.x < FF) {
        atomicAdd(&stats[f],      sd[0][0][f] + sd[0][1][f] + sd[0][2][f] + sd[0][3][f]);
        atomicAdd(&stats[FF + f], sd[1][0][f] + sd[1][1][f] + sd[1][2][f] + sd[1][3][f]);
    }
}

// xn = bn1(h); pS[n*128+2f+{0,1}] = xn@{Wf,Ws}_src + {bf,bs}; pD likewise (dst rows)
// Barrier-free wave-local staging; BN affine inline from raw sums.
__global__ __launch_bounds__(256) void node_kernel(
    const float* __restrict__ h, const float* __restrict__ stats,
    const float* __restrict__ gbn, const float* __restrict__ bbn,
    const float* __restrict__ Wf, const float* __restrict__ Ws,
    const float* __restrict__ bf, const float* __restrict__ bs,
    float* __restrict__ xn, float* __restrict__ pS, float* __restrict__ pD)
{
    __shared__ float sx[4][FF];
    const int lane = threadIdx.x & 63;
    const int w = threadIdx.x >> 6;
    const float* W = (w < 2) ? Wf : Ws;
    const int rowbase = (w & 1) * FF;
    float wr[FF];
#pragma unroll
    for (int k = 0; k < FF; ++k) wr[k] = W[(rowbase + k) * FF + lane];
    const float inv = 1.f / (float)NN;
    const float mean = stats[lane] * inv;
    const float var = stats[FF + lane] * inv - mean * mean;
    const float A = rsqrtf(var + 1e-5f) * gbn[lane];
    const float B = fmaf(-mean, A, bbn[lane]);
    float bias = 0.f;
    if (w == 0) bias = bf[lane];
    if (w == 2) bias = bs[lane];
    float* outp = ((w & 1) ? pD : pS) + ((w >> 1) & 1);
    for (int n = blockIdx.x; n < NN; n += gridDim.x) {
        const float xv = fmaf(h[n * FF + lane], A, B);
        if (w == 0) xn[n * FF + lane] = xv;
        sx[w][lane] = xv;                     // own row; wave-order DS, no barrier
        float acc = bias;
#pragma unroll
        for (int k4 = 0; k4 < FF / 4; ++k4) {
            float4 q = *(const float4*)&sx[w][k4 * 4];
            acc = fmaf(q.x, wr[k4 * 4 + 0], acc);
            acc = fmaf(q.y, wr[k4 * 4 + 1], acc);
            acc = fmaf(q.z, wr[k4 * 4 + 2], acc);
            acc = fmaf(q.w, wr[k4 * 4 + 3], acc);
        }
        outp[(size_t)n * 128 + 2 * lane] = acc;
    }
}

// MFMA edge kernel (R6-proven config): 64 sorted edges per wave-batch, 4 groups
// of 16 (M=16). gate/core via v_mfma_f32_16x16x32_bf16, K=64 in 2 steps.
// Epilogue adds fp32 node projections, m=sig*softplus, stage to LDS, segmented
// sum over sorted src runs, per-run-head atomicAdd.
__global__ __launch_bounds__(256) __attribute__((amdgpu_waves_per_eu(4, 4)))
void edge_kernel(const ushort* __restrict__ eaP, const int4* __restrict__ esd,
                 const ushort* __restrict__ wB,
                 const float* __restrict__ pS, const float* __restrict__ pD,
                 float* __restrict__ agg)
{
    __shared__ ushort wlds[WBSZ];           // 16 KB packed B-fragments
    __shared__ float  mld[4][64 * 17 + 4];  // per-wave m staging
    __shared__ int    sld[4][64];
    __shared__ int    dld[4][64];
    const int t = threadIdx.x, lane = t & 63, w = t >> 6;
    for (int i = t; i < WBSZ / 8; i += 256)
        ((int4*)wlds)[i] = ((const int4*)wB)[i];
    __syncthreads();
    const int le = lane >> 4, lf = lane & 15;
    const int nw = (gridDim.x * 256) >> 6;
    const int gw = (blockIdx.x * 256 + t) >> 6;

    for (int b = gw; b < NBATCH; b += nw) {
        const int pos = b * 64 + lane;
        const int4 rec = esd[pos];
        sld[w][lane] = rec.y;
        dld[w][lane] = rec.z;
        bf16x8 af[4][2];
#pragma unroll
        for (int g = 0; g < 4; ++g)
#pragma unroll
            for (int t2 = 0; t2 < 2; ++t2)
                af[g][t2] = *(const bf16x8*)&eaP[(((size_t)(b * 4 + g) * 2 + t2) * 64 + lane) * 8];

#pragma unroll
        for (int p = 0; p < 4; ++p) {
            const bf16x8 bG0 = *(const bf16x8*)&wlds[((0 * 8 + p) * 64 + lane) * 8];
            const bf16x8 bG1 = *(const bf16x8*)&wlds[((1 * 8 + p) * 64 + lane) * 8];
            const bf16x8 bC0 = *(const bf16x8*)&wlds[((0 * 8 + p + 4) * 64 + lane) * 8];
            const bf16x8 bC1 = *(const bf16x8*)&wlds[((1 * 8 + p + 4) * 64 + lane) * 8];
            const int f = p * 16 + lf;
#pragma unroll
            for (int g = 0; g < 4; ++g) {
                f32x4 aG = {0.f, 0.f, 0.f, 0.f}, aC = {0.f, 0.f, 0.f, 0.f};
                aG = __builtin_amdgcn_mfma_f32_16x16x32_bf16(af[g][0], bG0, aG, 0, 0, 0);
                aG = __builtin_amdgcn_mfma_f32_16x16x32_bf16(af[g][1], bG1, aG, 0, 0, 0);
                aC = __builtin_amdgcn_mfma_f32_16x16x32_bf16(af[g][0], bC0, aC, 0, 0, 0);
                aC = __builtin_amdgcn_mfma_f32_16x16x32_bf16(af[g][1], bC1, aC, 0, 0, 0);
                const int eb = g * 16 + le * 4;   // C/D row = 4*(lane>>4)+r
#pragma unroll
                for (int r = 0; r < 4; ++r) {
                    const int eidx = eb + r;
                    const int sv = sld[w][eidx];
                    const int dv = dld[w][eidx];
                    const float2 s2 = *(const float2*)(pS + (size_t)sv * 128 + 2 * f);
                    const float2 d2 = *(const float2*)(pD + (size_t)dv * 128 + 2 * f);
                    mld[w][eidx * 17 + lf] =
                        sigmoidf(aG[r] + s2.x + d2.x) * softplusf(aC[r] + s2.y + d2.y);
                }
            }
            const int f0 = p * 16;
            for (int s = 0; s < 16; ++s) {
                const int eidx = s * 4 + le;
                float v = mld[w][eidx * 17 + lf];
                const int sA = sld[w][eidx];
                const int sB = (le <= 2) ? sld[w][eidx + 1] : -1;
                const int sC = (le <= 1) ? sld[w][eidx + 2] : -1;
                const float t1 = __shfl_down(v, 16, 64);
                if (sB == sA) v += t1;
                const float t2v = __shfl_down(v, 32, 64);
                if (sC == sA) v += t2v;
                const bool head = (le == 0) || (sld[w][eidx - 1] != sA);
                if (head) unsafeAtomicAdd(&agg[(size_t)sA * FF + f0 + lf], v);
            }
        }
    }
}

// h = softplus(bn2(agg) + xn); BN affine from raw sums; fused stats for next
// conv's bn1; last conv pools
__global__ __launch_bounds__(256) void update_kernel(
    const float* __restrict__ agg, const float* __restrict__ xn,
    const float* __restrict__ stats,
    const float* __restrict__ gbn, const float* __restrict__ bbn,
    float* __restrict__ h, const int* __restrict__ batch,
    float* __restrict__ pool, float* __restrict__ pcnt,
    float* __restrict__ statsNext, const int do_pool)
{
    __shared__ float sdr[2][4][FF];
    const int myf = threadIdx.x & 63;
    const float inv = 1.f / (float)NN;
    const float mean = stats[myf] * inv;
    const float var = stats[FF + myf] * inv - mean * mean;
    const float A = rsqrtf(var + 1e-5f) * gbn[myf];
    const float B = fmaf(-mean, A, bbn[myf]);
    float s = 0.f, s2 = 0.f;
    const int total = NN * FF;
    for (int idx = blockIdx.x * blockDim.x + threadIdx.x; idx < total;
         idx += gridDim.x * blockDim.x) {
        const int n = idx >> 6;
        const float v = softplusf(fmaf(agg[idx], A, B) + xn[idx]);
        if (do_pool) {
            const int g = batch[n];
            unsafeAtomicAdd(&pool[g * FF + myf], v);
            if (myf == 0) unsafeAtomicAdd(&pcnt[g], 1.f);
        } else {
            h[idx] = v;
            s += v;
            s2 = fmaf(v, v, s2);
        }
    }
    if (!do_pool) {
        const int r = threadIdx.x >> 6;
        sdr[0][r][myf] = s;
        sdr[1][r][myf] = s2;
        __syncthreads();
        if (threadIdx.x < FF) {
            atomicAdd(&statsNext[myf],      sdr[0][0][myf] + sdr[0][1][myf] + sdr[0][2][myf] + sdr[0][3][myf]);
            atomicAdd(&statsNext[FF + myf], sdr[1][0][myf] + sdr[1][1][myf] + sdr[1][2][myf] + sdr[1][3][myf]);
        }
    }
}

__global__ __launch_bounds__(128) void readout_kernel(
    const float* __restrict__ pool, const float* __restrict__ pcnt,
    const float* __restrict__ fc1W, const float* __restrict__ fc1b,
    const float* __restrict__ outW, const float* __restrict__ outb,
    float* __restrict__ out)
{
    __shared__ float sp[FF];
    __shared__ float red[2];
    const int g = blockIdx.x;
    const int t = threadIdx.x;
    if (t < FF) {
        const float c = fmaxf(pcnt[g], 1.f);
        sp[t] = softplusf(pool[g * FF + t] / c);
    }
    __syncthreads();
    float a = fc1b[t];
#pragma unroll
    for (int k = 0; k < FF; ++k) a = fmaf(sp[k], fc1W[k * HH + t], a);
    float o = softplusf(a) * outW[t];
#pragma unroll
    for (int off = 32; off > 0; off >>= 1) o += __shfl_down(o, off, 64);
    if ((t & 63) == 0) red[t >> 6] = o;
    __syncthreads();
    if (t == 0) out[g] = red[0] + red[1] + outb[0];
}

extern "C" void kernel_launch(void* const* d_in, const int* in_sizes, int n_in,
                              void* d_out, int out_size, void* d_ws, size_t ws_size,
                              hipStream_t stream)
{
    const float* x     = (const float*)d_in[0];
    const int*   ei    = (const int*)  d_in[1];
    const float* ea    = (const float*)d_in[2];
    const int*   batch = (const int*)  d_in[3];
    const float* embW  = (const float*)d_in[4];
    const float* embb  = (const float*)d_in[5];
    const float* bn1g  = (const float*)d_in[6];
    const float* bn1b  = (const float*)d_in[7];
    const float* bn2g  = (const float*)d_in[8];
    const float* bn2b  = (const float*)d_in[9];
    const float* lnfW  = (const float*)d_in[10];
    const float* lnfb  = (const float*)d_in[11];
    const float* lnsW  = (const float*)d_in[12];
    const float* lnsb  = (const float*)d_in[13];
    const float* fc1W  = (const float*)d_in[14];
    const float* fc1b  = (const float*)d_in[15];
    const float* outW  = (const float*)d_in[16];
    const float* outb  = (const float*)d_in[17];

    float* ws      = (float*)d_ws;
    float* h       = ws;
    float* xn      = h   + (size_t)NN * FF;
    float* pS      = xn  + (size_t)NN * FF;      // [NN][128] interleaved gate/core
    float* pD      = pS  + (size_t)NN * 128;
    float* agg     = pD  + (size_t)NN * 128;
    float* pool    = agg + (size_t)NN * FF;
    float* pcnt    = pool + (size_t)NG * FF;
    float* statsB1 = pcnt + NG;                  // 3 x 256 (raw sums)
    float* statsB2 = statsB1 + 3 * 256;          // 3 x 256 (raw sums)
    int*   cnt     = (int*)(statsB2 + 3 * 256);  // NN
    int*   cursor  = cnt + NN;                   // NN
    int*   bsum    = cursor + NN;                // 256
    int4*  esd     = (int4*)(bsum + 256);        // NE x 16B
    ushort* wB     = (ushort*)(esd + NE);        // 3 * WBSZ
    ushort* eaP    = wB + 3 * WBSZ;              // NE * 64 bf16 (sorted order)

    hipMemsetAsync(cnt, 0, NN * sizeof(int), stream);
    hipMemsetAsync(pool, 0, (NG * FF + NG + 6 * 256) * sizeof(float), stream);

    hist_kernel<<<2048, 256, 0, stream>>>(ei, cnt);
    scan1_kernel<<<NBLK_SCAN, 256, 0, stream>>>(cnt, bsum);
    scan2_kernel<<<1, 256, 0, stream>>>(bsum);
    scan3_kernel<<<NBLK_SCAN, 256, 0, stream>>>(cnt, bsum, cursor);
    scatter_kernel<<<2048, 256, 0, stream>>>(ei, cursor, esd);
    pack_kernel<<<(NE + 255) / 256, 256, 0, stream>>>(ea, esd, eaP);
    prep_kernel<<<96, 256, 0, stream>>>(lnfW, lnsW, wB);
    emb_kernel<<<2048, 256, 0, stream>>>(x, embW, embb, h, statsB1);

    for (int i = 0; i < 3; ++i) {
        const float* Wf  = lnfW + (size_t)i * 169 * FF;
        const float* Wsp = lnsW + (size_t)i * 169 * FF;
        float* s1 = statsB1 + (size_t)i * 256;
        float* s2 = statsB2 + (size_t)i * 256;
        node_kernel<<<2048, 256, 0, stream>>>(h, s1, bn1g + i * FF, bn1b + i * FF,
                                              Wf, Wsp, lnfb + i * FF, lnsb + i * FF,
                                              xn, pS, pD);
        hipMemsetAsync(agg, 0, (size_t)NN * FF * sizeof(float), stream);
        edge_kernel<<<1024, 256, 0, stream>>>(eaP, esd, wB + (size_t)i * WBSZ,
                                              pS, pD, agg);
        stats_kernel<<<1024, 256, 0, stream>>>(agg, s2);
        update_kernel<<<2048, 256, 0, stream>>>(agg, xn, s2, bn2g + i * FF, bn2b + i * FF,
                                                h, batch, pool, pcnt,
                                                statsB1 + (size_t)(i + 1 < 3 ? i + 1 : 0) * 256,
                                                (i == 2) ? 1 : 0);
    }
    readout_kernel<<<NG, HH, 0, stream>>>(pool, pcnt, fc1W, fc1b, outW, outb, (float*)d_out);
}